// Round 2
// baseline (650.023 us; speedup 1.0000x reference)
//
#include <hip/hip_runtime.h>
#include <hip/hip_bf16.h>

// ---------------------------------------------------------------------------
// 2-layer GraphConv (DGL norm='both') + mean_nodes pool + linear classifier.
// N=80000 nodes, E=1.28M edges, D=H=64, C=5, G=512.
// ALL float tensors are fp32 (reference declares jnp.float32; round-0 NaN was
// caused by misreading them as bf16). Indices are int32.
// ---------------------------------------------------------------------------

// broadcast lane k's value of v to all lanes (k compile-time const after unroll)
__device__ __forceinline__ float lanebcast(float v, int k) {
    return __int_as_float(__builtin_amdgcn_readlane(__float_as_int(v), k));
}

// --- degree counting (scattered int atomics, ~16 hits/address) -------------
__global__ __launch_bounds__(256) void deg_kernel(
    const int* __restrict__ src, const int* __restrict__ dst,
    int* __restrict__ outdeg, int* __restrict__ indeg, int E)
{
    int i = blockIdx.x * 256 + threadIdx.x;
    int stride = gridDim.x * 256;
    for (int e = i; e < E; e += stride) {
        atomicAdd(&outdeg[src[e]], 1);
        atomicAdd(&indeg[dst[e]], 1);
    }
}

// --- norms + CSR row-start allocation (wave-aggregated global cursor) ------
__global__ __launch_bounds__(256) void norm_kernel(
    const int* __restrict__ outdeg, const int* __restrict__ indeg,
    float* __restrict__ nsrc, float* __restrict__ ndst,
    int* __restrict__ row_offs, int* __restrict__ cursor,
    int* __restrict__ counter, int N)
{
    int n = blockIdx.x * 256 + threadIdx.x;
    int lane = threadIdx.x & 63;
    int d = 0;
    if (n < N) {
        int od = outdeg[n], id = indeg[n];
        nsrc[n] = rsqrtf((float)max(od, 1));
        ndst[n] = rsqrtf((float)max(id, 1));
        d = id;
    }
    // wave-wide inclusive scan of d
    int x = d;
    #pragma unroll
    for (int off = 1; off < 64; off <<= 1) {
        int v = __shfl_up(x, off);
        if (lane >= off) x += v;
    }
    int tot = __shfl(x, 63);          // wave total
    int base = 0;
    if (lane == 0) base = atomicAdd(counter, tot);   // 1250 atomics total, not 80000
    base = __shfl(base, 0);
    if (n < N) {
        int s = base + x - d;          // exclusive within wave
        row_offs[n] = s;
        cursor[n] = s;
    }
}

// --- bucket src ids into per-dst CSR lists ---------------------------------
__global__ __launch_bounds__(256) void fill_kernel(
    const int* __restrict__ src, const int* __restrict__ dst,
    int* __restrict__ cursor, int* __restrict__ col, int E)
{
    int i = blockIdx.x * 256 + threadIdx.x;
    int stride = gridDim.x * 256;
    for (int e = i; e < E; e += stride) {
        int p = atomicAdd(&cursor[dst[e]], 1);
        col[p] = src[e];
    }
}

// --- graph boundaries from sorted graph_ids (no atomics, no scan) ----------
__global__ __launch_bounds__(256) void bounds_kernel(
    const int* __restrict__ gids, int* __restrict__ goffs, int N, int G)
{
    int i = blockIdx.x * 256 + threadIdx.x;
    if (i >= N) return;
    int b = gids[i];
    if (i == 0) {
        for (int g = 0; g <= b; g++) goffs[g] = 0;
    } else {
        int a = gids[i - 1];
        for (int g = a + 1; g <= b; g++) goffs[g] = i;
    }
    if (i == N - 1) {
        for (int g = b + 1; g <= G; g++) goffs[g] = N;
    }
}

// --- fused GraphConv: gather-sum + norm + (64x64 matvec) + bias + ReLU -----
// one wave per node; lane = feature index. W column j=lane lives in registers.
__global__ __launch_bounds__(256) void conv_kernel(
    const float* __restrict__ x, float* __restrict__ y,
    const int* __restrict__ col, const int* __restrict__ row_offs,
    const int* __restrict__ indeg, const float* __restrict__ nsrc,
    const float* __restrict__ ndst, const float* __restrict__ W,
    const float* __restrict__ b, int N)
{
    int lane = threadIdx.x & 63;
    float wcol[64];
    #pragma unroll
    for (int k = 0; k < 64; k++) wcol[k] = W[k * 64 + lane];   // coalesced
    float bias = b[lane];

    int wid = (blockIdx.x * 256 + threadIdx.x) >> 6;
    int nw  = (gridDim.x * 256) >> 6;
    for (int node = wid; node < N; node += nw) {
        int start = row_offs[node];
        int cnt   = indeg[node];
        float acc = 0.f;
        for (int e0 = 0; e0 < cnt; e0 += 64) {
            int m = min(cnt - e0, 64);
            int idx = 0; float nsl = 0.f;
            if (lane < m) {                     // vector-load a chunk of edge ids
                idx = col[start + e0 + lane];
                nsl = nsrc[idx];
            }
            for (int i = 0; i < m; i++) {
                int   s  = __shfl(idx, i);      // broadcast edge src + its norm
                float nv = __shfl(nsl, i);
                acc += x[(size_t)s * 64 + lane] * nv;   // 64-lane coalesced row
            }
        }
        acc *= ndst[node];
        // out[lane] = bias + sum_k acc_k * W[k][lane], 4 ILP partials
        float o0 = bias, o1 = 0.f, o2 = 0.f, o3 = 0.f;
        #pragma unroll
        for (int k = 0; k < 64; k += 4) {
            o0 += lanebcast(acc, k)     * wcol[k];
            o1 += lanebcast(acc, k + 1) * wcol[k + 1];
            o2 += lanebcast(acc, k + 2) * wcol[k + 2];
            o3 += lanebcast(acc, k + 3) * wcol[k + 3];
        }
        float o = (o0 + o1) + (o2 + o3);
        y[(size_t)node * 64 + lane] = fmaxf(o, 0.f);
    }
}

// --- per-graph mean pool + 64x5 classifier ---------------------------------
__global__ __launch_bounds__(256) void pool_kernel(
    const float* __restrict__ h2, const int* __restrict__ goffs,
    const float* __restrict__ Wc, const float* __restrict__ bc,
    float* __restrict__ out, int G)
{
    int lane = threadIdx.x & 63;
    int wid = (blockIdx.x * 256 + threadIdx.x) >> 6;
    int nw  = (gridDim.x * 256) >> 6;
    float wc[5];
    #pragma unroll
    for (int c = 0; c < 5; c++) wc[c] = Wc[lane * 5 + c];
    for (int g = wid; g < G; g += nw) {
        int s = goffs[g], e = goffs[g + 1];
        float acc = 0.f;
        for (int i = s; i < e; i++) acc += h2[(size_t)i * 64 + lane];
        float mean = acc / (float)max(e - s, 1);
        #pragma unroll
        for (int c = 0; c < 5; c++) {
            float p = mean * wc[c];
            #pragma unroll
            for (int off = 32; off; off >>= 1) p += __shfl_down(p, off);
            if (lane == 0) out[g * 5 + c] = p + bc[c];
        }
    }
}

extern "C" void kernel_launch(void* const* d_in, const int* in_sizes, int n_in,
                              void* d_out, int out_size, void* d_ws, size_t ws_size,
                              hipStream_t stream)
{
    const float* h    = (const float*)d_in[0];
    const int*   src  = (const int*)d_in[1];
    const int*   dst  = (const int*)d_in[2];
    const int*   gids = (const int*)d_in[3];
    const float* W1   = (const float*)d_in[4];
    const float* b1   = (const float*)d_in[5];
    const float* W2   = (const float*)d_in[6];
    const float* b2   = (const float*)d_in[7];
    const float* Wc   = (const float*)d_in[8];
    const float* bc   = (const float*)d_in[9];
    float* out = (float*)d_out;

    const int N = in_sizes[0] / 64;
    const int E = in_sizes[1];
    const int G = out_size / 5;

    // workspace carve (all 4B-aligned accesses only)
    char* p = (char*)d_ws;
    int* outdeg   = (int*)p;  p += (size_t)N * 4;
    int* indeg    = (int*)p;  p += (size_t)N * 4;
    int* counter  = (int*)p;  p += 4;
    size_t zero_bytes = (size_t)(2 * N + 1) * 4;     // everything above
    int* row_offs = (int*)p;  p += (size_t)N * 4;
    int* cursor   = (int*)p;  p += (size_t)N * 4;
    int* goffs    = (int*)p;  p += (size_t)(G + 1) * 4;
    float* nsrc   = (float*)p; p += (size_t)N * 4;
    float* ndst   = (float*)p; p += (size_t)N * 4;
    int* col      = (int*)p;  p += (size_t)E * 4;
    float* h1     = (float*)p; p += (size_t)N * 64 * 4;
    float* h2     = (float*)p; p += (size_t)N * 64 * 4;

    hipMemsetAsync(d_ws, 0, zero_bytes, stream);

    deg_kernel<<<1024, 256, 0, stream>>>(src, dst, outdeg, indeg, E);
    norm_kernel<<<(N + 255) / 256, 256, 0, stream>>>(outdeg, indeg, nsrc, ndst,
                                                     row_offs, cursor, counter, N);
    fill_kernel<<<1024, 256, 0, stream>>>(src, dst, cursor, col, E);
    bounds_kernel<<<(N + 255) / 256, 256, 0, stream>>>(gids, goffs, N, G);

    conv_kernel<<<2048, 256, 0, stream>>>(
        h, h1, col, row_offs, indeg, nsrc, ndst, W1, b1, N);
    conv_kernel<<<2048, 256, 0, stream>>>(
        h1, h2, col, row_offs, indeg, nsrc, ndst, W2, b2, N);

    pool_kernel<<<128, 256, 0, stream>>>(h2, goffs, Wc, bc, out, G);
}

// Round 3
// 478.569 us; speedup vs baseline: 1.3583x; 1.3583x over previous
//
#include <hip/hip_runtime.h>
#include <hip/hip_bf16.h>

// ---------------------------------------------------------------------------
// 2-layer GraphConv (DGL norm='both') + mean_nodes pool + linear classifier.
// N=80000, E=1.28M, D=H=64, C=5, G=512. fp32 everywhere.
// R2->R3: float4 gather (4 edges in flight / instr), pre-scaled sources
// (removes per-edge nsrc gather), block-per-graph pool.
// ---------------------------------------------------------------------------

__device__ __forceinline__ float lanebcast(float v, int k) {
    return __int_as_float(__builtin_amdgcn_readlane(__float_as_int(v), k));
}

// --- degree counting -------------------------------------------------------
__global__ __launch_bounds__(256) void deg_kernel(
    const int* __restrict__ src, const int* __restrict__ dst,
    int* __restrict__ outdeg, int* __restrict__ indeg, int E)
{
    int i = blockIdx.x * 256 + threadIdx.x;
    int stride = gridDim.x * 256;
    for (int e = i; e < E; e += stride) {
        atomicAdd(&outdeg[src[e]], 1);
        atomicAdd(&indeg[dst[e]], 1);
    }
}

// --- norms + CSR row-start allocation (wave-aggregated global cursor) ------
__global__ __launch_bounds__(256) void norm_kernel(
    const int* __restrict__ outdeg, const int* __restrict__ indeg,
    float* __restrict__ nsrc, float* __restrict__ ndst,
    int* __restrict__ row_offs, int* __restrict__ cursor,
    int* __restrict__ counter, int N)
{
    int n = blockIdx.x * 256 + threadIdx.x;
    int lane = threadIdx.x & 63;
    int d = 0;
    if (n < N) {
        int od = outdeg[n], id = indeg[n];
        nsrc[n] = rsqrtf((float)max(od, 1));
        ndst[n] = rsqrtf((float)max(id, 1));
        d = id;
    }
    int x = d;
    #pragma unroll
    for (int off = 1; off < 64; off <<= 1) {
        int v = __shfl_up(x, off);
        if (lane >= off) x += v;
    }
    int tot = __shfl(x, 63);
    int base = 0;
    if (lane == 0) base = atomicAdd(counter, tot);
    base = __shfl(base, 0);
    if (n < N) {
        int s = base + x - d;
        row_offs[n] = s;
        cursor[n] = s;
    }
}

// --- bucket src ids into per-dst CSR lists ---------------------------------
__global__ __launch_bounds__(256) void fill_kernel(
    const int* __restrict__ src, const int* __restrict__ dst,
    int* __restrict__ cursor, int* __restrict__ col, int E)
{
    int i = blockIdx.x * 256 + threadIdx.x;
    int stride = gridDim.x * 256;
    for (int e = i; e < E; e += stride) {
        int p = atomicAdd(&cursor[dst[e]], 1);
        col[p] = src[e];
    }
}

// --- graph boundaries from sorted graph_ids --------------------------------
__global__ __launch_bounds__(256) void bounds_kernel(
    const int* __restrict__ gids, int* __restrict__ goffs, int N, int G)
{
    int i = blockIdx.x * 256 + threadIdx.x;
    if (i >= N) return;
    int b = gids[i];
    if (i == 0) {
        for (int g = 0; g <= b; g++) goffs[g] = 0;
    } else {
        int a = gids[i - 1];
        for (int g = a + 1; g <= b; g++) goffs[g] = i;
    }
    if (i == N - 1) {
        for (int g = b + 1; g <= G; g++) goffs[g] = N;
    }
}

// --- xs = h * nsrc (row-broadcast), float4 streaming -----------------------
__global__ __launch_bounds__(256) void prescale_kernel(
    const float* __restrict__ h, const float* __restrict__ nsrc,
    float* __restrict__ xs, int n4)   // n4 = N*64/4
{
    int i = blockIdx.x * 256 + threadIdx.x;
    if (i >= n4) return;
    float s = nsrc[i >> 4];           // 16 float4 per row
    float4 v = ((const float4*)h)[i];
    v.x *= s; v.y *= s; v.z *= s; v.w *= s;
    ((float4*)xs)[i] = v;
}

// --- fused GraphConv: float4 gather-sum + 64x64 matvec + bias + ReLU -------
// one wave per node. Gather: sub=lane>>4 picks one of 4 concurrent edges,
// li=lane&15 picks the float4 within the 256B row. Matvec: lane = out feature.
__global__ __launch_bounds__(256) void conv_kernel(
    const float* __restrict__ xs,     // pre-scaled source rows
    float* __restrict__ y,
    const int* __restrict__ col, const int* __restrict__ row_offs,
    const int* __restrict__ indeg, const float* __restrict__ nsrc,
    const float* __restrict__ ndst, const float* __restrict__ W,
    const float* __restrict__ b, int N, int scale_out)
{
    int lane = threadIdx.x & 63;
    int sub  = lane >> 4;
    int li   = lane & 15;
    float wcol[64];
    #pragma unroll
    for (int k = 0; k < 64; k++) wcol[k] = W[k * 64 + lane];
    float bias = b[lane];
    const float4* xs4 = (const float4*)xs;

    int wid = (blockIdx.x * 256 + threadIdx.x) >> 6;
    int nw  = (gridDim.x * 256) >> 6;
    for (int node = wid; node < N; node += nw) {
        int start = row_offs[node];
        int cnt   = indeg[node];
        float4 acc = make_float4(0.f, 0.f, 0.f, 0.f);
        for (int e0 = 0; e0 < cnt; e0 += 64) {
            int m = min(cnt - e0, 64);
            int idx = 0;
            if (lane < m) idx = col[start + e0 + lane];
            for (int i = 0; i < m; i += 4) {
                int e  = i + sub;
                int s  = __shfl(idx, min(e, m - 1));   // uniform-flow shfl
                if (e < m) {
                    float4 v = xs4[s * 16 + li];
                    acc.x += v.x; acc.y += v.y; acc.z += v.z; acc.w += v.w;
                }
            }
        }
        // reduce the 4 sub-groups (xor 16, 32) -> every lane holds full sums
        #pragma unroll
        for (int off = 16; off <= 32; off <<= 1) {
            acc.x += __shfl_xor(acc.x, off);
            acc.y += __shfl_xor(acc.y, off);
            acc.z += __shfl_xor(acc.z, off);
            acc.w += __shfl_xor(acc.w, off);
        }
        float nd = ndst[node];
        acc.x *= nd; acc.y *= nd; acc.z *= nd; acc.w *= nd;
        // out[lane] = bias + sum_k acc_k * W[k][lane]; acc_k lives at
        // lane q=k>>2, component k&3 (valid on all subs after xor-reduce).
        float o0 = bias, o1 = 0.f, o2 = 0.f, o3 = 0.f;
        #pragma unroll
        for (int q = 0; q < 16; q++) {
            o0 += lanebcast(acc.x, q) * wcol[4 * q];
            o1 += lanebcast(acc.y, q) * wcol[4 * q + 1];
            o2 += lanebcast(acc.z, q) * wcol[4 * q + 2];
            o3 += lanebcast(acc.w, q) * wcol[4 * q + 3];
        }
        float o = fmaxf((o0 + o1) + (o2 + o3), 0.f);
        if (scale_out) o *= nsrc[node];   // pre-scale for next layer's gather
        y[node * 64 + lane] = o;
    }
}

// --- per-graph mean pool + 64x5 classifier (block per graph) ---------------
__global__ __launch_bounds__(256) void pool_kernel(
    const float* __restrict__ h2, const int* __restrict__ goffs,
    const float* __restrict__ Wc, const float* __restrict__ bc,
    float* __restrict__ out)
{
    int g = blockIdx.x;
    int lane = threadIdx.x & 63;
    int w = threadIdx.x >> 6;
    int s = goffs[g], e = goffs[g + 1];
    float acc = 0.f;
    for (int i = s + w; i < e; i += 4) acc += h2[i * 64 + lane];
    __shared__ float red[4][64];
    red[w][lane] = acc;
    __syncthreads();
    if (w == 0) {
        float tot = red[0][lane] + red[1][lane] + red[2][lane] + red[3][lane];
        float mean = tot / (float)max(e - s, 1);
        float wc[5];
        #pragma unroll
        for (int c = 0; c < 5; c++) wc[c] = Wc[lane * 5 + c];
        #pragma unroll
        for (int c = 0; c < 5; c++) {
            float p = mean * wc[c];
            #pragma unroll
            for (int off = 32; off; off >>= 1) p += __shfl_down(p, off);
            if (lane == 0) out[g * 5 + c] = p + bc[c];
        }
    }
}

extern "C" void kernel_launch(void* const* d_in, const int* in_sizes, int n_in,
                              void* d_out, int out_size, void* d_ws, size_t ws_size,
                              hipStream_t stream)
{
    const float* h    = (const float*)d_in[0];
    const int*   src  = (const int*)d_in[1];
    const int*   dst  = (const int*)d_in[2];
    const int*   gids = (const int*)d_in[3];
    const float* W1   = (const float*)d_in[4];
    const float* b1   = (const float*)d_in[5];
    const float* W2   = (const float*)d_in[6];
    const float* b2   = (const float*)d_in[7];
    const float* Wc   = (const float*)d_in[8];
    const float* bc   = (const float*)d_in[9];
    float* out = (float*)d_out;

    const int N = in_sizes[0] / 64;
    const int E = in_sizes[1];
    const int G = out_size / 5;

    char* p = (char*)d_ws;
    int* outdeg   = (int*)p;  p += (size_t)N * 4;
    int* indeg    = (int*)p;  p += (size_t)N * 4;
    int* counter  = (int*)p;  p += 4;
    size_t zero_bytes = (size_t)(2 * N + 1) * 4;
    int* row_offs = (int*)p;  p += (size_t)N * 4;
    int* cursor   = (int*)p;  p += (size_t)N * 4;
    int* goffs    = (int*)p;  p += (size_t)(G + 1) * 4;
    float* nsrc   = (float*)p; p += (size_t)N * 4;
    float* ndst   = (float*)p; p += (size_t)N * 4;
    int* col      = (int*)p;  p += (size_t)E * 4;
    float* h1     = (float*)p; p += (size_t)N * 64 * 4;
    float* h2     = (float*)p; p += (size_t)N * 64 * 4;
    float* xs     = h2;   // alias: xs dead before conv2 writes h2

    hipMemsetAsync(d_ws, 0, zero_bytes, stream);

    deg_kernel<<<2048, 256, 0, stream>>>(src, dst, outdeg, indeg, E);
    norm_kernel<<<(N + 255) / 256, 256, 0, stream>>>(outdeg, indeg, nsrc, ndst,
                                                     row_offs, cursor, counter, N);
    fill_kernel<<<2048, 256, 0, stream>>>(src, dst, cursor, col, E);
    bounds_kernel<<<(N + 255) / 256, 256, 0, stream>>>(gids, goffs, N, G);
    prescale_kernel<<<(N * 16 + 255) / 256, 256, 0, stream>>>(h, nsrc, xs, N * 16);

    conv_kernel<<<2048, 256, 0, stream>>>(
        xs, h1, col, row_offs, indeg, nsrc, ndst, W1, b1, N, 1);
    conv_kernel<<<2048, 256, 0, stream>>>(
        h1, h2, col, row_offs, indeg, nsrc, ndst, W2, b2, N, 0);

    pool_kernel<<<G, 256, 0, stream>>>(h2, goffs, Wc, bc, out);
}

// Round 4
// 341.896 us; speedup vs baseline: 1.9012x; 1.3997x over previous
//
#include <hip/hip_runtime.h>
#include <hip/hip_bf16.h>

// ---------------------------------------------------------------------------
// 2-layer GraphConv (DGL norm='both') + mean_nodes pool + linear classifier.
// N=80000, E=1.28M, D=H=64, C=5, G=512.
// R3->R4: (a) deg+fill fused into one fixed-slot CSR pass (SLOT=64; max indeg
// ~40 for Binomial(1.28M,1/80k)) -- kills the separate degree pass whose
// scattered device-scope atomics were ~100us; (b) gather tables stored bf16
// (pre-scaled by nsrc), halving the latency-bound gather footprint; fp32
// accumulation throughout, so only table rounding (~0.2% rel) enters.
// ---------------------------------------------------------------------------

#define SLOT 64

__device__ __forceinline__ float lanebcast(float v, int k) {
    return __int_as_float(__builtin_amdgcn_readlane(__float_as_int(v), k));
}
__device__ __forceinline__ float bflo(unsigned u) { return __uint_as_float(u << 16); }
__device__ __forceinline__ float bfhi(unsigned u) { return __uint_as_float(u & 0xffff0000u); }
__device__ __forceinline__ float bf1(unsigned short u) { return __uint_as_float((unsigned)u << 16); }
__device__ __forceinline__ unsigned short f2bf(float f) {   // RNE
    unsigned u = __float_as_uint(f);
    return (unsigned short)((u + 0x7fff + ((u >> 16) & 1)) >> 16);
}

// --- fused degree-count + slot-CSR fill (single pass over edges) -----------
__global__ __launch_bounds__(256) void fill_kernel(
    const int* __restrict__ src, const int* __restrict__ dst,
    int* __restrict__ cnt_out, int* __restrict__ cnt_in,
    int* __restrict__ col, int E)
{
    int i = blockIdx.x * 256 + threadIdx.x;
    int stride = gridDim.x * 256;
    int e4 = E >> 2;
    const int4* s4 = (const int4*)src;
    const int4* d4 = (const int4*)dst;
    for (int e = i; e < e4; e += stride) {
        int4 s = s4[e];
        int4 d = d4[e];
        atomicAdd(&cnt_out[s.x], 1);
        atomicAdd(&cnt_out[s.y], 1);
        atomicAdd(&cnt_out[s.z], 1);
        atomicAdd(&cnt_out[s.w], 1);
        int p0 = atomicAdd(&cnt_in[d.x], 1);
        int p1 = atomicAdd(&cnt_in[d.y], 1);
        int p2 = atomicAdd(&cnt_in[d.z], 1);
        int p3 = atomicAdd(&cnt_in[d.w], 1);
        if (p0 < SLOT) col[d.x * SLOT + p0] = s.x;
        if (p1 < SLOT) col[d.y * SLOT + p1] = s.y;
        if (p2 < SLOT) col[d.z * SLOT + p2] = s.z;
        if (p3 < SLOT) col[d.w * SLOT + p3] = s.w;
    }
    for (int e = (e4 << 2) + i; e < E; e += stride) {   // tail (E%4 != 0)
        int s = src[e], d = dst[e];
        atomicAdd(&cnt_out[s], 1);
        int p = atomicAdd(&cnt_in[d], 1);
        if (p < SLOT) col[d * SLOT + p] = s;
    }
}

// --- norms (pure elementwise now; no scan needed) --------------------------
__global__ __launch_bounds__(256) void norm_kernel(
    const int* __restrict__ cnt_out, const int* __restrict__ cnt_in,
    float* __restrict__ nsrc, float* __restrict__ ndst, int N)
{
    int n = blockIdx.x * 256 + threadIdx.x;
    if (n >= N) return;
    nsrc[n] = rsqrtf((float)max(cnt_out[n], 1));
    ndst[n] = rsqrtf((float)max(cnt_in[n], 1));
}

// --- graph boundaries from sorted graph_ids --------------------------------
__global__ __launch_bounds__(256) void bounds_kernel(
    const int* __restrict__ gids, int* __restrict__ goffs, int N, int G)
{
    int i = blockIdx.x * 256 + threadIdx.x;
    if (i >= N) return;
    int b = gids[i];
    if (i == 0) {
        for (int g = 0; g <= b; g++) goffs[g] = 0;
    } else {
        int a = gids[i - 1];
        for (int g = a + 1; g <= b; g++) goffs[g] = i;
    }
    if (i == N - 1) {
        for (int g = b + 1; g <= G; g++) goffs[g] = N;
    }
}

// --- xs_bf16 = bf16(h * nsrc), 2 elems/thread ------------------------------
__global__ __launch_bounds__(256) void prescale_kernel(
    const float* __restrict__ h, const float* __restrict__ nsrc,
    unsigned short* __restrict__ xs, int n2)   // n2 = N*32
{
    int i = blockIdx.x * 256 + threadIdx.x;
    if (i >= n2) return;
    float s = nsrc[i >> 5];                    // 32 float2 per row
    float2 v = ((const float2*)h)[i];
    ushort2 o;
    o.x = f2bf(v.x * s);
    o.y = f2bf(v.y * s);
    ((ushort2*)xs)[i] = o;
}

// --- fused GraphConv: bf16 gather-sum + 64x64 matvec + bias + ReLU ---------
// one wave per node. sub=lane>>3 picks one of 8 concurrent edges; li=lane&7
// picks 16B (8 bf16 feats) within the 128B row. fp32 accumulate.
__global__ __launch_bounds__(256) void conv_kernel(
    const unsigned short* __restrict__ xs,   // N x 64 bf16, pre-scaled by nsrc
    unsigned short* __restrict__ y,          // N x 64 bf16 out
    const int* __restrict__ col, const int* __restrict__ cnt_in,
    const float* __restrict__ nsrc, const float* __restrict__ ndst,
    const float* __restrict__ W, const float* __restrict__ b,
    int N, int scale_out)
{
    int lane = threadIdx.x & 63;
    int sub  = lane >> 3;
    int li   = lane & 7;
    float wcol[64];
    #pragma unroll
    for (int k = 0; k < 64; k++) wcol[k] = W[k * 64 + lane];
    float bias = b[lane];
    const uint4* x4 = (const uint4*)xs;      // row = 8 x uint4 (128B)

    int wid = (blockIdx.x * 256 + threadIdx.x) >> 6;
    int nw  = (gridDim.x * 256) >> 6;
    for (int node = wid; node < N; node += nw) {
        int cnt = min(cnt_in[node], SLOT);
        int idx = 0;
        if (lane < cnt) idx = col[node * SLOT + lane];
        float a0=0.f,a1=0.f,a2=0.f,a3=0.f,a4=0.f,a5=0.f,a6=0.f,a7=0.f;
        for (int i = 0; i < cnt; i += 8) {
            int e = i + sub;
            int s = __shfl(idx, min(e, cnt - 1));   // uniform flow, valid lane
            if (e < cnt) {
                uint4 v = x4[s * 8 + li];
                a0 += bflo(v.x); a1 += bfhi(v.x);
                a2 += bflo(v.y); a3 += bfhi(v.y);
                a4 += bflo(v.z); a5 += bfhi(v.z);
                a6 += bflo(v.w); a7 += bfhi(v.w);
            }
        }
        // reduce across the 8 sub-groups: lanes with equal li sum up.
        #pragma unroll
        for (int off = 8; off <= 32; off <<= 1) {
            a0 += __shfl_xor(a0, off); a1 += __shfl_xor(a1, off);
            a2 += __shfl_xor(a2, off); a3 += __shfl_xor(a3, off);
            a4 += __shfl_xor(a4, off); a5 += __shfl_xor(a5, off);
            a6 += __shfl_xor(a6, off); a7 += __shfl_xor(a7, off);
        }
        // feature k = q*8+r lives on lane q (li=q, sub=0), slot r.
        float o0 = 0.f, o1 = 0.f, o2 = 0.f, o3 = 0.f;
        #pragma unroll
        for (int q = 0; q < 8; q++) {
            o0 += lanebcast(a0, q) * wcol[q * 8 + 0];
            o1 += lanebcast(a1, q) * wcol[q * 8 + 1];
            o2 += lanebcast(a2, q) * wcol[q * 8 + 2];
            o3 += lanebcast(a3, q) * wcol[q * 8 + 3];
            o0 += lanebcast(a4, q) * wcol[q * 8 + 4];
            o1 += lanebcast(a5, q) * wcol[q * 8 + 5];
            o2 += lanebcast(a6, q) * wcol[q * 8 + 6];
            o3 += lanebcast(a7, q) * wcol[q * 8 + 7];
        }
        float o = fmaxf(bias + ndst[node] * ((o0 + o1) + (o2 + o3)), 0.f);
        if (scale_out) o *= nsrc[node];      // pre-scale for next layer
        y[node * 64 + lane] = f2bf(o);
    }
}

// --- per-graph mean pool + 64x5 classifier (block per graph) ---------------
__global__ __launch_bounds__(256) void pool_kernel(
    const unsigned short* __restrict__ h2, const int* __restrict__ goffs,
    const float* __restrict__ Wc, const float* __restrict__ bc,
    float* __restrict__ out)
{
    int g = blockIdx.x;
    int lane = threadIdx.x & 63;
    int w = threadIdx.x >> 6;
    int s = goffs[g], e = goffs[g + 1];
    float acc = 0.f;
    for (int i = s + w; i < e; i += 4) acc += bf1(h2[i * 64 + lane]);
    __shared__ float red[4][64];
    red[w][lane] = acc;
    __syncthreads();
    if (w == 0) {
        float tot = red[0][lane] + red[1][lane] + red[2][lane] + red[3][lane];
        float mean = tot / (float)max(e - s, 1);
        float wc[5];
        #pragma unroll
        for (int c = 0; c < 5; c++) wc[c] = Wc[lane * 5 + c];
        #pragma unroll
        for (int c = 0; c < 5; c++) {
            float p = mean * wc[c];
            #pragma unroll
            for (int off = 32; off; off >>= 1) p += __shfl_down(p, off);
            if (lane == 0) out[g * 5 + c] = p + bc[c];
        }
    }
}

extern "C" void kernel_launch(void* const* d_in, const int* in_sizes, int n_in,
                              void* d_out, int out_size, void* d_ws, size_t ws_size,
                              hipStream_t stream)
{
    const float* h    = (const float*)d_in[0];
    const int*   src  = (const int*)d_in[1];
    const int*   dst  = (const int*)d_in[2];
    const int*   gids = (const int*)d_in[3];
    const float* W1   = (const float*)d_in[4];
    const float* b1   = (const float*)d_in[5];
    const float* W2   = (const float*)d_in[6];
    const float* b2   = (const float*)d_in[7];
    const float* Wc   = (const float*)d_in[8];
    const float* bc   = (const float*)d_in[9];
    float* out = (float*)d_out;

    const int N = in_sizes[0] / 64;
    const int E = in_sizes[1];
    const int G = out_size / 5;

    // workspace carve, 256B-aligned buffers
    auto align = [](size_t x) { return (x + 255) & ~(size_t)255; };
    char* p = (char*)d_ws;
    int* cnt_out = (int*)p;            p += align((size_t)N * 4);
    int* cnt_in  = (int*)p;            p += align((size_t)N * 4);
    size_t zero_bytes = (size_t)((char*)p - (char*)d_ws);   // both counters
    float* nsrc  = (float*)p;          p += align((size_t)N * 4);
    float* ndst  = (float*)p;          p += align((size_t)N * 4);
    int* goffs   = (int*)p;            p += align((size_t)(G + 1) * 4);
    int* col     = (int*)p;            p += align((size_t)N * SLOT * 4);
    unsigned short* h1s = (unsigned short*)p; p += align((size_t)N * 64 * 2);
    unsigned short* xs  = (unsigned short*)p; p += align((size_t)N * 64 * 2);
    unsigned short* h2  = xs;          // alias: xs dead after conv1

    hipMemsetAsync(d_ws, 0, zero_bytes, stream);

    fill_kernel<<<1024, 256, 0, stream>>>(src, dst, cnt_out, cnt_in, col, E);
    norm_kernel<<<(N + 255) / 256, 256, 0, stream>>>(cnt_out, cnt_in, nsrc, ndst, N);
    bounds_kernel<<<(N + 255) / 256, 256, 0, stream>>>(gids, goffs, N, G);
    prescale_kernel<<<(N * 32 + 255) / 256, 256, 0, stream>>>(h, nsrc, xs, N * 32);

    conv_kernel<<<2048, 256, 0, stream>>>(
        xs, h1s, col, cnt_in, nsrc, ndst, W1, b1, N, 1);
    conv_kernel<<<2048, 256, 0, stream>>>(
        h1s, h2, col, cnt_in, nsrc, ndst, W2, b2, N, 0);

    pool_kernel<<<G, 256, 0, stream>>>(h2, goffs, Wc, bc, out);
}

// Round 5
// 272.705 us; speedup vs baseline: 2.3836x; 1.2537x over previous
//
#include <hip/hip_runtime.h>
#include <hip/hip_bf16.h>

// ---------------------------------------------------------------------------
// 2-layer GraphConv (DGL norm='both') + mean_nodes pool + linear classifier.
// N=80000, E=1.28M, D=H=64, C=5, G=512.
// R4->R5: CSR construction rebuilt atomic-free. R4's fill_kernel spent 135us
// on 2.56M scattered device-scope atomics (~31B HBM RMW each, ~900GB/s
// ceiling). Replaced by a 512-node-bucket radix: LDS histograms + LDS scans +
// LDS-cursor scatter, producing a packed CSR (row_offs+col) and both norms.
// Zero global atomics, zero memset. Conv reads packed CSR (chunked, generic
// for any indegree). bf16 gather tables (pre-scaled by nsrc) as in R4.
// ---------------------------------------------------------------------------

#define NBK 160            // max buckets: ceil(80000/512)=157 <= 160

__device__ __forceinline__ float lanebcast(float v, int k) {
    return __int_as_float(__builtin_amdgcn_readlane(__float_as_int(v), k));
}
__device__ __forceinline__ float bflo(unsigned u) { return __uint_as_float(u << 16); }
__device__ __forceinline__ float bfhi(unsigned u) { return __uint_as_float(u & 0xffff0000u); }
__device__ __forceinline__ float bf1(unsigned short u) { return __uint_as_float((unsigned)u << 16); }
__device__ __forceinline__ unsigned short f2bf(float f) {   // RNE
    unsigned u = __float_as_uint(f);
    return (unsigned short)((u + 0x7fff + ((u >> 16) & 1)) >> 16);
}

// --- P1: per-block bucket histograms of dst (edges) and src (degrees) ------
__global__ __launch_bounds__(256) void p1_hist(
    const int* __restrict__ src, const int* __restrict__ dst,
    int* __restrict__ histD, int* __restrict__ histS, int E, int NB)
{
    __shared__ int hd[NBK], hs[NBK];
    for (int i = threadIdx.x; i < NB; i += 256) { hd[i] = 0; hs[i] = 0; }
    __syncthreads();
    int chunk = (E + gridDim.x - 1) / gridDim.x;
    int s0 = blockIdx.x * chunk, s1 = min(E, s0 + chunk);
    for (int i = s0 + threadIdx.x; i < s1; i += 256) {
        atomicAdd(&hd[dst[i] >> 9], 1);
        atomicAdd(&hs[src[i] >> 9], 1);
    }
    __syncthreads();
    for (int b = threadIdx.x; b < NB; b += 256) {
        histD[b * 256 + blockIdx.x] = hd[b];
        histS[b * 256 + blockIdx.x] = hs[b];
    }
}

// --- P2: per-bucket exclusive scan over the 256 block counts (in-place) ----
__global__ __launch_bounds__(256) void p2_scanblocks(
    int* __restrict__ histD, int* __restrict__ histS,
    int* __restrict__ btotD, int* __restrict__ btotS, int NB)
{
    int b = blockIdx.x;
    bool dmode = b < NB;
    int* h = dmode ? (histD + b * 256) : (histS + (b - NB) * 256);
    int t = threadIdx.x, lane = t & 63, w = t >> 6;
    int v = h[t];
    int x = v;
    #pragma unroll
    for (int off = 1; off < 64; off <<= 1) {
        int y = __shfl_up(x, off);
        if (lane >= off) x += y;
    }
    __shared__ int wt[4];
    if (lane == 63) wt[w] = x;
    __syncthreads();
    int bw = 0;
    for (int i = 0; i < w; i++) bw += wt[i];
    h[t] = x - v + bw;                       // exclusive
    if (t == 255) (dmode ? btotD : btotS)[dmode ? b : b - NB] = x + bw;
}

// --- P3: scan bucket totals -> bucket bases (single block) -----------------
__global__ __launch_bounds__(256) void p3_scanbuckets(
    const int* __restrict__ btotD, const int* __restrict__ btotS,
    int* __restrict__ baseD, int* __restrict__ baseS,
    int* __restrict__ row_offs, int E, int NB, int N)
{
    __shared__ int wt[4];
    int t = threadIdx.x, lane = t & 63, w = t >> 6;
    // dst buckets
    int v = (t < NB) ? btotD[t] : 0;
    int x = v;
    #pragma unroll
    for (int off = 1; off < 64; off <<= 1) {
        int y = __shfl_up(x, off);
        if (lane >= off) x += y;
    }
    if (lane == 63) wt[w] = x;
    __syncthreads();
    int bw = 0;
    for (int i = 0; i < w; i++) bw += wt[i];
    if (t <= NB) baseD[t] = x - v + bw;
    __syncthreads();
    // src buckets
    v = (t < NB) ? btotS[t] : 0;
    x = v;
    #pragma unroll
    for (int off = 1; off < 64; off <<= 1) {
        int y = __shfl_up(x, off);
        if (lane >= off) x += y;
    }
    if (lane == 63) wt[w] = x;
    __syncthreads();
    bw = 0;
    for (int i = 0; i < w; i++) bw += wt[i];
    if (t <= NB) baseS[t] = x - v + bw;
    if (t == 0) row_offs[N] = E;
}

// --- P4: scatter edges into dst-buckets (packed) + src locals --------------
// pack word = (dst&511)<<17 | src  (src < 2^17). LDS cursors, no global atomics.
__global__ __launch_bounds__(256) void p4_scatter(
    const int* __restrict__ src, const int* __restrict__ dst,
    const int* __restrict__ histD, const int* __restrict__ histS,
    const int* __restrict__ baseD, const int* __restrict__ baseS,
    int* __restrict__ pack, unsigned short* __restrict__ sloc, int E, int NB)
{
    __shared__ int cd[NBK], cs[NBK];
    for (int b = threadIdx.x; b < NB; b += 256) {
        cd[b] = baseD[b] + histD[b * 256 + blockIdx.x];
        cs[b] = baseS[b] + histS[b * 256 + blockIdx.x];
    }
    __syncthreads();
    int chunk = (E + gridDim.x - 1) / gridDim.x;
    int s0 = blockIdx.x * chunk, s1 = min(E, s0 + chunk);
    for (int i = s0 + threadIdx.x; i < s1; i += 256) {
        int s = src[i], d = dst[i];
        int pd = atomicAdd(&cd[d >> 9], 1);          // LDS atomic
        pack[pd] = ((d & 511) << 17) | s;
        int ps = atomicAdd(&cs[s >> 9], 1);          // LDS atomic
        sloc[ps] = (unsigned short)(s & 511);
    }
}

// --- P5: per-bucket CSR build (dst mode) / out-degree norms (src mode) -----
__global__ __launch_bounds__(256) void p5_build(
    const int* __restrict__ pack, const unsigned short* __restrict__ sloc,
    const int* __restrict__ baseD, const int* __restrict__ baseS,
    int* __restrict__ col, int* __restrict__ row_offs,
    float* __restrict__ nsrc, float* __restrict__ ndst, int N, int NB)
{
    __shared__ int hist[512];
    __shared__ int wt[4];
    int t = threadIdx.x;
    bool dmode = blockIdx.x < NB;
    int b = dmode ? blockIdx.x : blockIdx.x - NB;
    int n0 = b << 9, n1 = min(N, n0 + 512);
    hist[t] = 0; hist[t + 256] = 0;
    __syncthreads();
    int e0 = dmode ? baseD[b] : baseS[b];
    int e1 = dmode ? baseD[b + 1] : baseS[b + 1];
    if (!dmode) {
        for (int i = e0 + t; i < e1; i += 256)
            atomicAdd(&hist[sloc[i]], 1);            // LDS atomic
        __syncthreads();
        for (int n = n0 + t; n < n1; n += 256)
            nsrc[n] = rsqrtf((float)max(hist[n - n0], 1));
        return;
    }
    for (int i = e0 + t; i < e1; i += 256)
        atomicAdd(&hist[pack[i] >> 17], 1);          // LDS atomic
    __syncthreads();
    // exclusive scan of hist[0..511] (each thread owns a pair)
    int c0 = hist[2 * t], c1 = hist[2 * t + 1];
    int v = c0 + c1;
    int lane = t & 63, w = t >> 6;
    int x = v;
    #pragma unroll
    for (int off = 1; off < 64; off <<= 1) {
        int y = __shfl_up(x, off);
        if (lane >= off) x += y;
    }
    if (lane == 63) wt[w] = x;
    __syncthreads();
    int bw = 0;
    for (int i = 0; i < w; i++) bw += wt[i];
    int excl = x - v + bw;
    // row_offs + ndst for this pair of nodes
    int n = n0 + 2 * t;
    if (n < n1) {
        row_offs[n] = e0 + excl;
        ndst[n] = rsqrtf((float)max(c0, 1));
    }
    if (n + 1 < n1) {
        row_offs[n + 1] = e0 + excl + c0;
        ndst[n + 1] = rsqrtf((float)max(c1, 1));
    }
    hist[2 * t] = excl;                  // becomes placement cursor
    hist[2 * t + 1] = excl + c0;
    __syncthreads();
    for (int i = e0 + t; i < e1; i += 256) {
        int wd = pack[i];
        int pos = atomicAdd(&hist[wd >> 17], 1);     // LDS atomic
        col[e0 + pos] = wd & 0x1FFFF;
    }
}

// --- graph boundaries from sorted graph_ids --------------------------------
__global__ __launch_bounds__(256) void bounds_kernel(
    const int* __restrict__ gids, int* __restrict__ goffs, int N, int G)
{
    int i = blockIdx.x * 256 + threadIdx.x;
    if (i >= N) return;
    int b = gids[i];
    if (i == 0) {
        for (int g = 0; g <= b; g++) goffs[g] = 0;
    } else {
        int a = gids[i - 1];
        for (int g = a + 1; g <= b; g++) goffs[g] = i;
    }
    if (i == N - 1) {
        for (int g = b + 1; g <= G; g++) goffs[g] = N;
    }
}

// --- xs_bf16 = bf16(h * nsrc), 2 elems/thread ------------------------------
__global__ __launch_bounds__(256) void prescale_kernel(
    const float* __restrict__ h, const float* __restrict__ nsrc,
    unsigned short* __restrict__ xs, int n2)   // n2 = N*32
{
    int i = blockIdx.x * 256 + threadIdx.x;
    if (i >= n2) return;
    float s = nsrc[i >> 5];                    // 32 float2 per row
    float2 v = ((const float2*)h)[i];
    ushort2 o;
    o.x = f2bf(v.x * s);
    o.y = f2bf(v.y * s);
    ((ushort2*)xs)[i] = o;
}

// --- fused GraphConv: bf16 gather-sum + 64x64 matvec + bias + ReLU ---------
// one wave per node. sub=lane>>3 picks one of 8 concurrent edges; li=lane&7
// picks 16B (8 bf16 feats) within the 128B row. fp32 accumulate.
__global__ __launch_bounds__(256) void conv_kernel(
    const unsigned short* __restrict__ xs,   // N x 64 bf16, pre-scaled by nsrc
    unsigned short* __restrict__ y,          // N x 64 bf16 out
    const int* __restrict__ col, const int* __restrict__ row_offs,
    const float* __restrict__ nsrc, const float* __restrict__ ndst,
    const float* __restrict__ W, const float* __restrict__ b,
    int N, int scale_out)
{
    int lane = threadIdx.x & 63;
    int sub  = lane >> 3;
    int li   = lane & 7;
    float wcol[64];
    #pragma unroll
    for (int k = 0; k < 64; k++) wcol[k] = W[k * 64 + lane];
    float bias = b[lane];
    const uint4* x4 = (const uint4*)xs;      // row = 8 x uint4 (128B)

    int wid = (blockIdx.x * 256 + threadIdx.x) >> 6;
    int nw  = (gridDim.x * 256) >> 6;
    for (int node = wid; node < N; node += nw) {
        int ro0 = row_offs[node];
        int cnt = row_offs[node + 1] - ro0;
        float a0=0.f,a1=0.f,a2=0.f,a3=0.f,a4=0.f,a5=0.f,a6=0.f,a7=0.f;
        for (int c0 = 0; c0 < cnt; c0 += 64) {
            int m = min(cnt - c0, 64);
            int idx = 0;
            if (lane < m) idx = col[ro0 + c0 + lane];
            for (int i = 0; i < m; i += 8) {
                int e = i + sub;
                int s = __shfl(idx, min(e, m - 1));   // uniform flow
                if (e < m) {
                    uint4 v = x4[s * 8 + li];
                    a0 += bflo(v.x); a1 += bfhi(v.x);
                    a2 += bflo(v.y); a3 += bfhi(v.y);
                    a4 += bflo(v.z); a5 += bfhi(v.z);
                    a6 += bflo(v.w); a7 += bfhi(v.w);
                }
            }
        }
        // reduce across the 8 sub-groups
        #pragma unroll
        for (int off = 8; off <= 32; off <<= 1) {
            a0 += __shfl_xor(a0, off); a1 += __shfl_xor(a1, off);
            a2 += __shfl_xor(a2, off); a3 += __shfl_xor(a3, off);
            a4 += __shfl_xor(a4, off); a5 += __shfl_xor(a5, off);
            a6 += __shfl_xor(a6, off); a7 += __shfl_xor(a7, off);
        }
        // feature k = q*8+r lives on lane q, slot r
        float o0 = 0.f, o1 = 0.f, o2 = 0.f, o3 = 0.f;
        #pragma unroll
        for (int q = 0; q < 8; q++) {
            o0 += lanebcast(a0, q) * wcol[q * 8 + 0];
            o1 += lanebcast(a1, q) * wcol[q * 8 + 1];
            o2 += lanebcast(a2, q) * wcol[q * 8 + 2];
            o3 += lanebcast(a3, q) * wcol[q * 8 + 3];
            o0 += lanebcast(a4, q) * wcol[q * 8 + 4];
            o1 += lanebcast(a5, q) * wcol[q * 8 + 5];
            o2 += lanebcast(a6, q) * wcol[q * 8 + 6];
            o3 += lanebcast(a7, q) * wcol[q * 8 + 7];
        }
        float o = fmaxf(bias + ndst[node] * ((o0 + o1) + (o2 + o3)), 0.f);
        if (scale_out) o *= nsrc[node];      // pre-scale for next layer
        y[node * 64 + lane] = f2bf(o);
    }
}

// --- per-graph mean pool + 64x5 classifier (block per graph) ---------------
__global__ __launch_bounds__(256) void pool_kernel(
    const unsigned short* __restrict__ h2, const int* __restrict__ goffs,
    const float* __restrict__ Wc, const float* __restrict__ bc,
    float* __restrict__ out)
{
    int g = blockIdx.x;
    int lane = threadIdx.x & 63;
    int w = threadIdx.x >> 6;
    int s = goffs[g], e = goffs[g + 1];
    float acc = 0.f;
    for (int i = s + w; i < e; i += 4) acc += bf1(h2[i * 64 + lane]);
    __shared__ float red[4][64];
    red[w][lane] = acc;
    __syncthreads();
    if (w == 0) {
        float tot = red[0][lane] + red[1][lane] + red[2][lane] + red[3][lane];
        float mean = tot / (float)max(e - s, 1);
        float wc[5];
        #pragma unroll
        for (int c = 0; c < 5; c++) wc[c] = Wc[lane * 5 + c];
        #pragma unroll
        for (int c = 0; c < 5; c++) {
            float p = mean * wc[c];
            #pragma unroll
            for (int off = 32; off; off >>= 1) p += __shfl_down(p, off);
            if (lane == 0) out[g * 5 + c] = p + bc[c];
        }
    }
}

extern "C" void kernel_launch(void* const* d_in, const int* in_sizes, int n_in,
                              void* d_out, int out_size, void* d_ws, size_t ws_size,
                              hipStream_t stream)
{
    const float* h    = (const float*)d_in[0];
    const int*   src  = (const int*)d_in[1];
    const int*   dst  = (const int*)d_in[2];
    const int*   gids = (const int*)d_in[3];
    const float* W1   = (const float*)d_in[4];
    const float* b1   = (const float*)d_in[5];
    const float* W2   = (const float*)d_in[6];
    const float* b2   = (const float*)d_in[7];
    const float* Wc   = (const float*)d_in[8];
    const float* bc   = (const float*)d_in[9];
    float* out = (float*)d_out;

    const int N = in_sizes[0] / 64;
    const int E = in_sizes[1];
    const int G = out_size / 5;
    const int NB = (N + 511) >> 9;         // 157 buckets of 512 node ids

    // workspace carve, 256B-aligned (no memset needed: all fully written)
    auto align = [](size_t x) { return (x + 255) & ~(size_t)255; };
    char* p = (char*)d_ws;
    int* histD   = (int*)p;            p += align((size_t)NBK * 256 * 4);
    int* histS   = (int*)p;            p += align((size_t)NBK * 256 * 4);
    int* btotD   = (int*)p;            p += align((size_t)NBK * 4);
    int* btotS   = (int*)p;            p += align((size_t)NBK * 4);
    int* baseD   = (int*)p;            p += align((size_t)(NBK + 1) * 4);
    int* baseS   = (int*)p;            p += align((size_t)(NBK + 1) * 4);
    int* row_offs= (int*)p;            p += align((size_t)(N + 1) * 4);
    float* nsrc  = (float*)p;          p += align((size_t)N * 4);
    float* ndst  = (float*)p;          p += align((size_t)N * 4);
    int* goffs   = (int*)p;            p += align((size_t)(G + 1) * 4);
    int* pack    = (int*)p;            p += align((size_t)E * 4);
    unsigned short* sloc = (unsigned short*)p; p += align((size_t)E * 2);
    int* col     = (int*)p;            p += align((size_t)E * 4);
    unsigned short* h1s = (unsigned short*)p; p += align((size_t)N * 64 * 2);
    unsigned short* xs  = (unsigned short*)p; p += align((size_t)N * 64 * 2);
    unsigned short* h2  = xs;          // alias: xs dead after conv1

    p1_hist<<<256, 256, 0, stream>>>(src, dst, histD, histS, E, NB);
    p2_scanblocks<<<2 * NB, 256, 0, stream>>>(histD, histS, btotD, btotS, NB);
    p3_scanbuckets<<<1, 256, 0, stream>>>(btotD, btotS, baseD, baseS,
                                          row_offs, E, NB, N);
    p4_scatter<<<256, 256, 0, stream>>>(src, dst, histD, histS, baseD, baseS,
                                        pack, sloc, E, NB);
    p5_build<<<2 * NB, 256, 0, stream>>>(pack, sloc, baseD, baseS, col,
                                         row_offs, nsrc, ndst, N, NB);
    bounds_kernel<<<(N + 255) / 256, 256, 0, stream>>>(gids, goffs, N, G);
    prescale_kernel<<<(N * 32 + 255) / 256, 256, 0, stream>>>(h, nsrc, xs, N * 32);

    conv_kernel<<<2048, 256, 0, stream>>>(
        xs, h1s, col, row_offs, nsrc, ndst, W1, b1, N, 1);
    conv_kernel<<<2048, 256, 0, stream>>>(
        h1s, h2, col, row_offs, nsrc, ndst, W2, b2, N, 0);

    pool_kernel<<<G, 256, 0, stream>>>(h2, goffs, Wc, bc, out);
}

// Round 6
// 238.640 us; speedup vs baseline: 2.7239x; 1.1427x over previous
//
#include <hip/hip_runtime.h>
#include <hip/hip_bf16.h>

// ---------------------------------------------------------------------------
// 2-layer GraphConv (DGL norm='both') + mean_nodes pool + linear classifier.
// N=80000, E=1.28M, D=H=64, C=5, G=512.
// R5->R6: aggregation commutes with @W, so the dense 64x64 matvec (~50% of
// the gather kernel's VALU work, measured VALUBusy 42% at 61us) is hoisted
// into a separate MFMA GEMM (z = x@W, 16x16x32 bf16). The gather kernel is
// now pure gather+reduce+epilogue with 16 edges in flight per wave.
// CSR build (atomic-free bucket radix) unchanged from R5.
// ---------------------------------------------------------------------------

#define NBK 160            // max buckets: ceil(80000/512)=157 <= 160

typedef __attribute__((ext_vector_type(8))) short bf16x8;
typedef __attribute__((ext_vector_type(4))) float f32x4;

__device__ __forceinline__ float bflo(unsigned u) { return __uint_as_float(u << 16); }
__device__ __forceinline__ float bfhi(unsigned u) { return __uint_as_float(u & 0xffff0000u); }
__device__ __forceinline__ float bf1(unsigned short u) { return __uint_as_float((unsigned)u << 16); }
__device__ __forceinline__ unsigned short f2bf(float f) {   // RNE
    unsigned u = __float_as_uint(f);
    return (unsigned short)((u + 0x7fff + ((u >> 16) & 1)) >> 16);
}
__device__ __forceinline__ unsigned packbf(float lo, float hi) {
    return (unsigned)f2bf(lo) | ((unsigned)f2bf(hi) << 16);
}

// --- P1: per-block bucket histograms of dst (edges) and src (degrees) ------
__global__ __launch_bounds__(256) void p1_hist(
    const int* __restrict__ src, const int* __restrict__ dst,
    int* __restrict__ histD, int* __restrict__ histS, int E, int NB)
{
    __shared__ int hd[NBK], hs[NBK];
    for (int i = threadIdx.x; i < NB; i += 256) { hd[i] = 0; hs[i] = 0; }
    __syncthreads();
    int chunk = (E + gridDim.x - 1) / gridDim.x;
    int s0 = blockIdx.x * chunk, s1 = min(E, s0 + chunk);
    for (int i = s0 + threadIdx.x; i < s1; i += 256) {
        atomicAdd(&hd[dst[i] >> 9], 1);
        atomicAdd(&hs[src[i] >> 9], 1);
    }
    __syncthreads();
    for (int b = threadIdx.x; b < NB; b += 256) {
        histD[b * 256 + blockIdx.x] = hd[b];
        histS[b * 256 + blockIdx.x] = hs[b];
    }
}

// --- P2: per-bucket exclusive scan over the 256 block counts (in-place) ----
__global__ __launch_bounds__(256) void p2_scanblocks(
    int* __restrict__ histD, int* __restrict__ histS,
    int* __restrict__ btotD, int* __restrict__ btotS, int NB)
{
    int b = blockIdx.x;
    bool dmode = b < NB;
    int* h = dmode ? (histD + b * 256) : (histS + (b - NB) * 256);
    int t = threadIdx.x, lane = t & 63, w = t >> 6;
    int v = h[t];
    int x = v;
    #pragma unroll
    for (int off = 1; off < 64; off <<= 1) {
        int y = __shfl_up(x, off);
        if (lane >= off) x += y;
    }
    __shared__ int wt[4];
    if (lane == 63) wt[w] = x;
    __syncthreads();
    int bw = 0;
    for (int i = 0; i < w; i++) bw += wt[i];
    h[t] = x - v + bw;                       // exclusive
    if (t == 255) (dmode ? btotD : btotS)[dmode ? b : b - NB] = x + bw;
}

// --- P3: scan bucket totals -> bucket bases (single block) -----------------
__global__ __launch_bounds__(256) void p3_scanbuckets(
    const int* __restrict__ btotD, const int* __restrict__ btotS,
    int* __restrict__ baseD, int* __restrict__ baseS,
    int* __restrict__ row_offs, int E, int NB, int N)
{
    __shared__ int wt[4];
    int t = threadIdx.x, lane = t & 63, w = t >> 6;
    int v = (t < NB) ? btotD[t] : 0;
    int x = v;
    #pragma unroll
    for (int off = 1; off < 64; off <<= 1) {
        int y = __shfl_up(x, off);
        if (lane >= off) x += y;
    }
    if (lane == 63) wt[w] = x;
    __syncthreads();
    int bw = 0;
    for (int i = 0; i < w; i++) bw += wt[i];
    if (t <= NB) baseD[t] = x - v + bw;
    __syncthreads();
    v = (t < NB) ? btotS[t] : 0;
    x = v;
    #pragma unroll
    for (int off = 1; off < 64; off <<= 1) {
        int y = __shfl_up(x, off);
        if (lane >= off) x += y;
    }
    if (lane == 63) wt[w] = x;
    __syncthreads();
    bw = 0;
    for (int i = 0; i < w; i++) bw += wt[i];
    if (t <= NB) baseS[t] = x - v + bw;
    if (t == 0) row_offs[N] = E;
}

// --- P4: scatter edges into dst-buckets (packed) + src locals --------------
__global__ __launch_bounds__(256) void p4_scatter(
    const int* __restrict__ src, const int* __restrict__ dst,
    const int* __restrict__ histD, const int* __restrict__ histS,
    const int* __restrict__ baseD, const int* __restrict__ baseS,
    int* __restrict__ pack, unsigned short* __restrict__ sloc, int E, int NB)
{
    __shared__ int cd[NBK], cs[NBK];
    for (int b = threadIdx.x; b < NB; b += 256) {
        cd[b] = baseD[b] + histD[b * 256 + blockIdx.x];
        cs[b] = baseS[b] + histS[b * 256 + blockIdx.x];
    }
    __syncthreads();
    int chunk = (E + gridDim.x - 1) / gridDim.x;
    int s0 = blockIdx.x * chunk, s1 = min(E, s0 + chunk);
    for (int i = s0 + threadIdx.x; i < s1; i += 256) {
        int s = src[i], d = dst[i];
        int pd = atomicAdd(&cd[d >> 9], 1);          // LDS atomic
        pack[pd] = ((d & 511) << 17) | s;
        int ps = atomicAdd(&cs[s >> 9], 1);          // LDS atomic
        sloc[ps] = (unsigned short)(s & 511);
    }
}

// --- P5: per-bucket CSR build (dst mode) / out-degree norms (src mode) -----
__global__ __launch_bounds__(256) void p5_build(
    const int* __restrict__ pack, const unsigned short* __restrict__ sloc,
    const int* __restrict__ baseD, const int* __restrict__ baseS,
    int* __restrict__ col, int* __restrict__ row_offs,
    float* __restrict__ nsrc, float* __restrict__ ndst, int N, int NB)
{
    __shared__ int hist[512];
    __shared__ int wt[4];
    int t = threadIdx.x;
    bool dmode = blockIdx.x < NB;
    int b = dmode ? blockIdx.x : blockIdx.x - NB;
    int n0 = b << 9, n1 = min(N, n0 + 512);
    hist[t] = 0; hist[t + 256] = 0;
    __syncthreads();
    int e0 = dmode ? baseD[b] : baseS[b];
    int e1 = dmode ? baseD[b + 1] : baseS[b + 1];
    if (!dmode) {
        for (int i = e0 + t; i < e1; i += 256)
            atomicAdd(&hist[sloc[i]], 1);            // LDS atomic
        __syncthreads();
        for (int n = n0 + t; n < n1; n += 256)
            nsrc[n] = rsqrtf((float)max(hist[n - n0], 1));
        return;
    }
    for (int i = e0 + t; i < e1; i += 256)
        atomicAdd(&hist[pack[i] >> 17], 1);          // LDS atomic
    __syncthreads();
    int c0 = hist[2 * t], c1 = hist[2 * t + 1];
    int v = c0 + c1;
    int lane = t & 63, w = t >> 6;
    int x = v;
    #pragma unroll
    for (int off = 1; off < 64; off <<= 1) {
        int y = __shfl_up(x, off);
        if (lane >= off) x += y;
    }
    if (lane == 63) wt[w] = x;
    __syncthreads();
    int bw = 0;
    for (int i = 0; i < w; i++) bw += wt[i];
    int excl = x - v + bw;
    int n = n0 + 2 * t;
    if (n < n1) {
        row_offs[n] = e0 + excl;
        ndst[n] = rsqrtf((float)max(c0, 1));
    }
    if (n + 1 < n1) {
        row_offs[n + 1] = e0 + excl + c0;
        ndst[n + 1] = rsqrtf((float)max(c1, 1));
    }
    hist[2 * t] = excl;
    hist[2 * t + 1] = excl + c0;
    __syncthreads();
    for (int i = e0 + t; i < e1; i += 256) {
        int wd = pack[i];
        int pos = atomicAdd(&hist[wd >> 17], 1);     // LDS atomic
        col[e0 + pos] = wd & 0x1FFFF;
    }
}

// --- graph boundaries from sorted graph_ids --------------------------------
__global__ __launch_bounds__(256) void bounds_kernel(
    const int* __restrict__ gids, int* __restrict__ goffs, int N, int G)
{
    int i = blockIdx.x * 256 + threadIdx.x;
    if (i >= N) return;
    int b = gids[i];
    if (i == 0) {
        for (int g = 0; g <= b; g++) goffs[g] = 0;
    } else {
        int a = gids[i - 1];
        for (int g = a + 1; g <= b; g++) goffs[g] = i;
    }
    if (i == N - 1) {
        for (int g = b + 1; g <= G; g++) goffs[g] = N;
    }
}

// --- xs_bf16 = bf16(h * nsrc), 2 elems/thread ------------------------------
__global__ __launch_bounds__(256) void prescale_kernel(
    const float* __restrict__ h, const float* __restrict__ nsrc,
    unsigned short* __restrict__ xs, int n2)   // n2 = N*32
{
    int i = blockIdx.x * 256 + threadIdx.x;
    if (i >= n2) return;
    float s = nsrc[i >> 5];                    // 32 float2 per row
    float2 v = ((const float2*)h)[i];
    ushort2 o;
    o.x = f2bf(v.x * s);
    o.y = f2bf(v.y * s);
    ((ushort2*)xs)[i] = o;
}

// --- dense GEMM: Z[Mx64] = A[Mx64] @ W[64x64], bf16 MFMA -------------------
// Block = 4 waves, each wave one 16-row M-tile (block covers 64 rows).
// A frag: lane holds A[m=lane&15][k=quad*8+j] = uint4 at row*128B + ks*64 +
// quad*16. B frag: B[k=ks*32+quad*8+j][n=nt*16+col] from fp32 W (cvt bf16).
// D: col=lane&15, row=quad*4+reg (verified layout, learn_hip m89/m91).
__global__ __launch_bounds__(256) void gemm_kernel(
    const unsigned short* __restrict__ A, const float* __restrict__ W,
    unsigned short* __restrict__ Z, int M)
{
    int t = threadIdx.x, lane = t & 63, w = t >> 6;
    int col = lane & 15, quad = lane >> 4;
    bf16x8 bfrag[4][2];
    #pragma unroll
    for (int nt = 0; nt < 4; nt++)
        #pragma unroll
        for (int ks = 0; ks < 2; ks++)
            #pragma unroll
            for (int j = 0; j < 8; j++)
                bfrag[nt][ks][j] =
                    (short)f2bf(W[(ks * 32 + quad * 8 + j) * 64 + nt * 16 + col]);

    int mbase = blockIdx.x * 64 + w * 16;
    if (mbase >= M) return;
    int row = min(mbase + col, M - 1);
    const uint4* a4 = (const uint4*)A;
    union { uint4 u; bf16x8 v; } a0, a1;
    a0.u = a4[(size_t)row * 8 + quad];       // k = quad*8+j   (ks=0)
    a1.u = a4[(size_t)row * 8 + 4 + quad];   // k = 32+quad*8+j (ks=1)

    #pragma unroll
    for (int nt = 0; nt < 4; nt++) {
        f32x4 acc = {0.f, 0.f, 0.f, 0.f};
        acc = __builtin_amdgcn_mfma_f32_16x16x32_bf16(a0.v, bfrag[nt][0], acc, 0, 0, 0);
        acc = __builtin_amdgcn_mfma_f32_16x16x32_bf16(a1.v, bfrag[nt][1], acc, 0, 0, 0);
        #pragma unroll
        for (int r = 0; r < 4; r++) {
            int m = mbase + quad * 4 + r;
            if (m < M) Z[(size_t)m * 64 + nt * 16 + col] = f2bf(acc[r]);
        }
    }
}

// --- pure gather-aggregate: acc = sum(z[col]); epilogue norm+bias+relu -----
// one wave per node; sub=lane>>3 in {0..7} = edge slot, li=lane&7 = 16B chunk
// of the 128B row. 16 edges in flight (two uint4 loads per iter). fp32 accum.
__global__ __launch_bounds__(256) void agg_kernel(
    const unsigned short* __restrict__ z,    // N x 64 bf16 (pre-GEMMed)
    unsigned short* __restrict__ y,          // N x 64 bf16 out
    const int* __restrict__ col, const int* __restrict__ row_offs,
    const float* __restrict__ nsrc, const float* __restrict__ ndst,
    const float* __restrict__ b, int N, int scale_out)
{
    int lane = threadIdx.x & 63;
    int sub  = lane >> 3;
    int li   = lane & 7;
    float4 bA = ((const float4*)b)[li * 2];        // b[li*8 + 0..3]
    float4 bB = ((const float4*)b)[li * 2 + 1];    // b[li*8 + 4..7]
    const uint4* x4 = (const uint4*)z;

    int wid = (blockIdx.x * 256 + threadIdx.x) >> 6;
    int nw  = (gridDim.x * 256) >> 6;
    for (int node = wid; node < N; node += nw) {
        int ro0 = row_offs[node];
        int cnt = row_offs[node + 1] - ro0;
        float a0=0.f,a1=0.f,a2=0.f,a3=0.f,a4=0.f,a5=0.f,a6=0.f,a7=0.f;
        for (int c0 = 0; c0 < cnt; c0 += 64) {
            int m = min(cnt - c0, 64);
            int idx = 0;
            if (lane < m) idx = col[ro0 + c0 + lane];
            for (int i = 0; i < m; i += 16) {
                int e1 = i + sub, e2 = i + 8 + sub;
                int s1 = __shfl(idx, min(e1, m - 1));
                int s2 = __shfl(idx, min(e2, m - 1));
                uint4 v1 = make_uint4(0u,0u,0u,0u), v2 = make_uint4(0u,0u,0u,0u);
                if (e1 < m) v1 = x4[(size_t)s1 * 8 + li];
                if (e2 < m) v2 = x4[(size_t)s2 * 8 + li];
                a0 += bflo(v1.x); a1 += bfhi(v1.x);
                a2 += bflo(v1.y); a3 += bfhi(v1.y);
                a4 += bflo(v1.z); a5 += bfhi(v1.z);
                a6 += bflo(v1.w); a7 += bfhi(v1.w);
                a0 += bflo(v2.x); a1 += bfhi(v2.x);
                a2 += bflo(v2.y); a3 += bfhi(v2.y);
                a4 += bflo(v2.z); a5 += bfhi(v2.z);
                a6 += bflo(v2.w); a7 += bfhi(v2.w);
            }
        }
        #pragma unroll
        for (int off = 8; off <= 32; off <<= 1) {
            a0 += __shfl_xor(a0, off); a1 += __shfl_xor(a1, off);
            a2 += __shfl_xor(a2, off); a3 += __shfl_xor(a3, off);
            a4 += __shfl_xor(a4, off); a5 += __shfl_xor(a5, off);
            a6 += __shfl_xor(a6, off); a7 += __shfl_xor(a7, off);
        }
        float nd = ndst[node];
        float o0 = fmaxf(nd * a0 + bA.x, 0.f);
        float o1 = fmaxf(nd * a1 + bA.y, 0.f);
        float o2 = fmaxf(nd * a2 + bA.z, 0.f);
        float o3 = fmaxf(nd * a3 + bA.w, 0.f);
        float o4 = fmaxf(nd * a4 + bB.x, 0.f);
        float o5 = fmaxf(nd * a5 + bB.y, 0.f);
        float o6 = fmaxf(nd * a6 + bB.z, 0.f);
        float o7 = fmaxf(nd * a7 + bB.w, 0.f);
        if (scale_out) {
            float s = nsrc[node];
            o0 *= s; o1 *= s; o2 *= s; o3 *= s;
            o4 *= s; o5 *= s; o6 *= s; o7 *= s;
        }
        if (sub == 0) {                       // 8 lanes store the 128B row
            uint4 o;
            o.x = packbf(o0, o1);
            o.y = packbf(o2, o3);
            o.z = packbf(o4, o5);
            o.w = packbf(o6, o7);
            ((uint4*)y)[(size_t)node * 8 + li] = o;
        }
    }
}

// --- per-graph mean pool + 64x5 classifier (block per graph) ---------------
__global__ __launch_bounds__(256) void pool_kernel(
    const unsigned short* __restrict__ h2, const int* __restrict__ goffs,
    const float* __restrict__ Wc, const float* __restrict__ bc,
    float* __restrict__ out)
{
    int g = blockIdx.x;
    int lane = threadIdx.x & 63;
    int w = threadIdx.x >> 6;
    int s = goffs[g], e = goffs[g + 1];
    float acc = 0.f;
    for (int i = s + w; i < e; i += 4) acc += bf1(h2[i * 64 + lane]);
    __shared__ float red[4][64];
    red[w][lane] = acc;
    __syncthreads();
    if (w == 0) {
        float tot = red[0][lane] + red[1][lane] + red[2][lane] + red[3][lane];
        float mean = tot / (float)max(e - s, 1);
        float wc[5];
        #pragma unroll
        for (int c = 0; c < 5; c++) wc[c] = Wc[lane * 5 + c];
        #pragma unroll
        for (int c = 0; c < 5; c++) {
            float p = mean * wc[c];
            #pragma unroll
            for (int off = 32; off; off >>= 1) p += __shfl_down(p, off);
            if (lane == 0) out[g * 5 + c] = p + bc[c];
        }
    }
}

extern "C" void kernel_launch(void* const* d_in, const int* in_sizes, int n_in,
                              void* d_out, int out_size, void* d_ws, size_t ws_size,
                              hipStream_t stream)
{
    const float* h    = (const float*)d_in[0];
    const int*   src  = (const int*)d_in[1];
    const int*   dst  = (const int*)d_in[2];
    const int*   gids = (const int*)d_in[3];
    const float* W1   = (const float*)d_in[4];
    const float* b1   = (const float*)d_in[5];
    const float* W2   = (const float*)d_in[6];
    const float* b2   = (const float*)d_in[7];
    const float* Wc   = (const float*)d_in[8];
    const float* bc   = (const float*)d_in[9];
    float* out = (float*)d_out;

    const int N = in_sizes[0] / 64;
    const int E = in_sizes[1];
    const int G = out_size / 5;
    const int NB = (N + 511) >> 9;

    auto align = [](size_t x) { return (x + 255) & ~(size_t)255; };
    char* p = (char*)d_ws;
    int* histD   = (int*)p;            p += align((size_t)NBK * 256 * 4);
    int* histS   = (int*)p;            p += align((size_t)NBK * 256 * 4);
    int* btotD   = (int*)p;            p += align((size_t)NBK * 4);
    int* btotS   = (int*)p;            p += align((size_t)NBK * 4);
    int* baseD   = (int*)p;            p += align((size_t)(NBK + 1) * 4);
    int* baseS   = (int*)p;            p += align((size_t)(NBK + 1) * 4);
    int* row_offs= (int*)p;            p += align((size_t)(N + 1) * 4);
    float* nsrc  = (float*)p;          p += align((size_t)N * 4);
    float* ndst  = (float*)p;          p += align((size_t)N * 4);
    int* goffs   = (int*)p;            p += align((size_t)(G + 1) * 4);
    int* pack    = (int*)p;            p += align((size_t)E * 4);
    unsigned short* sloc = (unsigned short*)p; p += align((size_t)E * 2);
    int* col     = (int*)p;            p += align((size_t)E * 4);
    unsigned short* xs  = (unsigned short*)p; p += align((size_t)N * 64 * 2);
    unsigned short* z1  = (unsigned short*)p; p += align((size_t)N * 64 * 2);
    unsigned short* h1s = (unsigned short*)p; p += align((size_t)N * 64 * 2);
    unsigned short* z2  = xs;   // alias: xs dead after gemm1
    unsigned short* h2  = z1;   // alias: z1 dead after conv1

    p1_hist<<<256, 256, 0, stream>>>(src, dst, histD, histS, E, NB);
    p2_scanblocks<<<2 * NB, 256, 0, stream>>>(histD, histS, btotD, btotS, NB);
    p3_scanbuckets<<<1, 256, 0, stream>>>(btotD, btotS, baseD, baseS,
                                          row_offs, E, NB, N);
    p4_scatter<<<256, 256, 0, stream>>>(src, dst, histD, histS, baseD, baseS,
                                        pack, sloc, E, NB);
    p5_build<<<2 * NB, 256, 0, stream>>>(pack, sloc, baseD, baseS, col,
                                         row_offs, nsrc, ndst, N, NB);
    bounds_kernel<<<(N + 255) / 256, 256, 0, stream>>>(gids, goffs, N, G);
    prescale_kernel<<<(N * 32 + 255) / 256, 256, 0, stream>>>(h, nsrc, xs, N * 32);

    gemm_kernel<<<(N + 63) / 64, 256, 0, stream>>>(xs, W1, z1, N);
    agg_kernel<<<2048, 256, 0, stream>>>(z1, h1s, col, row_offs,
                                         nsrc, ndst, b1, N, 1);
    gemm_kernel<<<(N + 63) / 64, 256, 0, stream>>>(h1s, W2, z2, N);
    agg_kernel<<<2048, 256, 0, stream>>>(z2, h2, col, row_offs,
                                         nsrc, ndst, b2, N, 0);

    pool_kernel<<<G, 256, 0, stream>>>(h2, goffs, Wc, bc, out);
}

// Round 7
// 238.382 us; speedup vs baseline: 2.7268x; 1.0011x over previous
//
#include <hip/hip_runtime.h>
#include <hip/hip_bf16.h>

// ---------------------------------------------------------------------------
// 2-layer GraphConv (DGL norm='both') + mean_nodes pool + linear classifier.
// N=80000, E=1.28M, D=H=64, C=5, G=512.
// R6->R7: (1) 12 -> 10 dispatches: bounds fused into p1 (extra blocks),
// prescale fused into p5 src-mode blocks (they already own the out-degree
// histogram). (2) layer re-associated to aggregate-then-GEMM; agg is a pure
// gather-sum (epilogue bias/relu/ndst/nsrc moved into the GEMM's MFMA
// epilogue, free on fp32 accumulators). (3) agg runs 32 edges in flight per
// wave (4 guarded uint4 loads/iter) against the measured latency bound.
// Note: the 44us fillBufferAligned in the profile is the harness's 268MB
// d_ws re-poison -- fixed overhead, already at HBM roofline.
// ---------------------------------------------------------------------------

#define NBK 160            // max buckets: ceil(80000/512)=157 <= 160
#define HB  256            // histogram blocks in p1

typedef __attribute__((ext_vector_type(8))) short bf16x8;
typedef __attribute__((ext_vector_type(4))) float f32x4;

__device__ __forceinline__ float bflo(unsigned u) { return __uint_as_float(u << 16); }
__device__ __forceinline__ float bfhi(unsigned u) { return __uint_as_float(u & 0xffff0000u); }
__device__ __forceinline__ float bf1(unsigned short u) { return __uint_as_float((unsigned)u << 16); }
__device__ __forceinline__ unsigned short f2bf(float f) {   // RNE
    unsigned u = __float_as_uint(f);
    return (unsigned short)((u + 0x7fff + ((u >> 16) & 1)) >> 16);
}
__device__ __forceinline__ unsigned packbf(float lo, float hi) {
    return (unsigned)f2bf(lo) | ((unsigned)f2bf(hi) << 16);
}

// --- P1: per-block bucket histograms (blocks < HB) + graph bounds (rest) ---
__global__ __launch_bounds__(256) void p1_hist(
    const int* __restrict__ src, const int* __restrict__ dst,
    int* __restrict__ histD, int* __restrict__ histS,
    const int* __restrict__ gids, int* __restrict__ goffs,
    int E, int NB, int N, int G)
{
    if (blockIdx.x >= HB) {                  // fused bounds_kernel
        int i = (blockIdx.x - HB) * 256 + threadIdx.x;
        if (i >= N) return;
        int b = gids[i];
        if (i == 0) {
            for (int g = 0; g <= b; g++) goffs[g] = 0;
        } else {
            int a = gids[i - 1];
            for (int g = a + 1; g <= b; g++) goffs[g] = i;
        }
        if (i == N - 1) {
            for (int g = b + 1; g <= G; g++) goffs[g] = N;
        }
        return;
    }
    __shared__ int hd[NBK], hs[NBK];
    for (int i = threadIdx.x; i < NB; i += 256) { hd[i] = 0; hs[i] = 0; }
    __syncthreads();
    int chunk = (E + HB - 1) / HB;
    int s0 = blockIdx.x * chunk, s1 = min(E, s0 + chunk);
    for (int i = s0 + threadIdx.x; i < s1; i += 256) {
        atomicAdd(&hd[dst[i] >> 9], 1);
        atomicAdd(&hs[src[i] >> 9], 1);
    }
    __syncthreads();
    for (int b = threadIdx.x; b < NB; b += 256) {
        histD[b * 256 + blockIdx.x] = hd[b];
        histS[b * 256 + blockIdx.x] = hs[b];
    }
}

// --- P2: per-bucket exclusive scan over the 256 block counts (in-place) ----
__global__ __launch_bounds__(256) void p2_scanblocks(
    int* __restrict__ histD, int* __restrict__ histS,
    int* __restrict__ btotD, int* __restrict__ btotS, int NB)
{
    int b = blockIdx.x;
    bool dmode = b < NB;
    int* h = dmode ? (histD + b * 256) : (histS + (b - NB) * 256);
    int t = threadIdx.x, lane = t & 63, w = t >> 6;
    int v = h[t];
    int x = v;
    #pragma unroll
    for (int off = 1; off < 64; off <<= 1) {
        int y = __shfl_up(x, off);
        if (lane >= off) x += y;
    }
    __shared__ int wt[4];
    if (lane == 63) wt[w] = x;
    __syncthreads();
    int bw = 0;
    for (int i = 0; i < w; i++) bw += wt[i];
    h[t] = x - v + bw;                       // exclusive
    if (t == 255) (dmode ? btotD : btotS)[dmode ? b : b - NB] = x + bw;
}

// --- P3: scan bucket totals -> bucket bases (single block) -----------------
__global__ __launch_bounds__(256) void p3_scanbuckets(
    const int* __restrict__ btotD, const int* __restrict__ btotS,
    int* __restrict__ baseD, int* __restrict__ baseS,
    int* __restrict__ row_offs, int E, int NB, int N)
{
    __shared__ int wt[4];
    int t = threadIdx.x, lane = t & 63, w = t >> 6;
    int v = (t < NB) ? btotD[t] : 0;
    int x = v;
    #pragma unroll
    for (int off = 1; off < 64; off <<= 1) {
        int y = __shfl_up(x, off);
        if (lane >= off) x += y;
    }
    if (lane == 63) wt[w] = x;
    __syncthreads();
    int bw = 0;
    for (int i = 0; i < w; i++) bw += wt[i];
    if (t <= NB) baseD[t] = x - v + bw;
    __syncthreads();
    v = (t < NB) ? btotS[t] : 0;
    x = v;
    #pragma unroll
    for (int off = 1; off < 64; off <<= 1) {
        int y = __shfl_up(x, off);
        if (lane >= off) x += y;
    }
    if (lane == 63) wt[w] = x;
    __syncthreads();
    bw = 0;
    for (int i = 0; i < w; i++) bw += wt[i];
    if (t <= NB) baseS[t] = x - v + bw;
    if (t == 0) row_offs[N] = E;
}

// --- P4: scatter edges into dst-buckets (packed) + src locals --------------
__global__ __launch_bounds__(256) void p4_scatter(
    const int* __restrict__ src, const int* __restrict__ dst,
    const int* __restrict__ histD, const int* __restrict__ histS,
    const int* __restrict__ baseD, const int* __restrict__ baseS,
    int* __restrict__ pack, unsigned short* __restrict__ sloc, int E, int NB)
{
    __shared__ int cd[NBK], cs[NBK];
    for (int b = threadIdx.x; b < NB; b += 256) {
        cd[b] = baseD[b] + histD[b * 256 + blockIdx.x];
        cs[b] = baseS[b] + histS[b * 256 + blockIdx.x];
    }
    __syncthreads();
    int chunk = (E + gridDim.x - 1) / gridDim.x;
    int s0 = blockIdx.x * chunk, s1 = min(E, s0 + chunk);
    for (int i = s0 + threadIdx.x; i < s1; i += 256) {
        int s = src[i], d = dst[i];
        int pd = atomicAdd(&cd[d >> 9], 1);          // LDS atomic
        pack[pd] = ((d & 511) << 17) | s;
        int ps = atomicAdd(&cs[s >> 9], 1);          // LDS atomic
        sloc[ps] = (unsigned short)(s & 511);
    }
}

// --- P5: dst mode -> CSR (row_offs,col,ndst); src mode -> nsrc + prescale --
__global__ __launch_bounds__(256) void p5_build(
    const int* __restrict__ pack, const unsigned short* __restrict__ sloc,
    const int* __restrict__ baseD, const int* __restrict__ baseS,
    int* __restrict__ col, int* __restrict__ row_offs,
    float* __restrict__ nsrc, float* __restrict__ ndst,
    const float* __restrict__ h, unsigned short* __restrict__ xs,
    int N, int NB)
{
    __shared__ int hist[512];
    __shared__ float nsl[512];
    __shared__ int wt[4];
    int t = threadIdx.x;
    bool dmode = blockIdx.x < NB;
    int b = dmode ? blockIdx.x : blockIdx.x - NB;
    int n0 = b << 9, n1 = min(N, n0 + 512);
    hist[t] = 0; hist[t + 256] = 0;
    __syncthreads();
    int e0 = dmode ? baseD[b] : baseS[b];
    int e1 = dmode ? baseD[b + 1] : baseS[b + 1];
    if (!dmode) {
        for (int i = e0 + t; i < e1; i += 256)
            atomicAdd(&hist[sloc[i]], 1);            // LDS atomic
        __syncthreads();
        for (int n = n0 + t; n < n1; n += 256) {
            float s = rsqrtf((float)max(hist[n - n0], 1));
            nsrc[n] = s;
            nsl[n - n0] = s;
        }
        __syncthreads();
        // fused prescale: xs[n] = bf16(h[n] * nsrc[n]) for this bucket
        int cnt = n1 - n0;
        const float2* h2p = (const float2*)h;
        ushort2* xp = (ushort2*)xs;
        for (int i = t; i < cnt * 32; i += 256) {
            int node = i >> 5;
            float s = nsl[node];
            float2 v = h2p[(size_t)(n0 + node) * 32 + (i & 31)];
            ushort2 o;
            o.x = f2bf(v.x * s);
            o.y = f2bf(v.y * s);
            xp[(size_t)(n0 + node) * 32 + (i & 31)] = o;
        }
        return;
    }
    for (int i = e0 + t; i < e1; i += 256)
        atomicAdd(&hist[pack[i] >> 17], 1);          // LDS atomic
    __syncthreads();
    int c0 = hist[2 * t], c1 = hist[2 * t + 1];
    int v = c0 + c1;
    int lane = t & 63, w = t >> 6;
    int x = v;
    #pragma unroll
    for (int off = 1; off < 64; off <<= 1) {
        int y = __shfl_up(x, off);
        if (lane >= off) x += y;
    }
    if (lane == 63) wt[w] = x;
    __syncthreads();
    int bw = 0;
    for (int i = 0; i < w; i++) bw += wt[i];
    int excl = x - v + bw;
    int n = n0 + 2 * t;
    if (n < n1) {
        row_offs[n] = e0 + excl;
        ndst[n] = rsqrtf((float)max(c0, 1));
    }
    if (n + 1 < n1) {
        row_offs[n + 1] = e0 + excl + c0;
        ndst[n + 1] = rsqrtf((float)max(c1, 1));
    }
    hist[2 * t] = excl;
    hist[2 * t + 1] = excl + c0;
    __syncthreads();
    for (int i = e0 + t; i < e1; i += 256) {
        int wd = pack[i];
        int pos = atomicAdd(&hist[wd >> 17], 1);     // LDS atomic
        col[e0 + pos] = wd & 0x1FFFF;
    }
}

// --- pure gather-sum: s[node] = sum over in-edges of z[src] ----------------
// one wave per node; sub=lane>>3 = edge slot, li=lane&7 = 16B chunk of the
// 128B row. 32 edges in flight (4 guarded uint4 loads/iter). fp32 accum.
__global__ __launch_bounds__(256) void agg_kernel(
    const unsigned short* __restrict__ z, unsigned short* __restrict__ y,
    const int* __restrict__ col, const int* __restrict__ row_offs, int N)
{
    int lane = threadIdx.x & 63;
    int sub  = lane >> 3;
    int li   = lane & 7;
    const uint4* x4 = (const uint4*)z;

    int wid = (blockIdx.x * 256 + threadIdx.x) >> 6;
    int nw  = (gridDim.x * 256) >> 6;
    for (int node = wid; node < N; node += nw) {
        int ro0 = row_offs[node];
        int cnt = row_offs[node + 1] - ro0;
        float a0=0.f,a1=0.f,a2=0.f,a3=0.f,a4=0.f,a5=0.f,a6=0.f,a7=0.f;
        for (int c0 = 0; c0 < cnt; c0 += 64) {
            int m = min(cnt - c0, 64);
            int idx = 0;
            if (lane < m) idx = col[ro0 + c0 + lane];
            for (int i = 0; i < m; i += 32) {
                int e1 = i + sub, e2 = i + 8 + sub, e3 = i + 16 + sub, e4 = i + 24 + sub;
                int s1 = __shfl(idx, min(e1, m - 1));
                int s2 = __shfl(idx, min(e2, m - 1));
                int s3 = __shfl(idx, min(e3, m - 1));
                int s4 = __shfl(idx, min(e4, m - 1));
                uint4 v1 = make_uint4(0u,0u,0u,0u), v2 = make_uint4(0u,0u,0u,0u);
                uint4 v3 = make_uint4(0u,0u,0u,0u), v4 = make_uint4(0u,0u,0u,0u);
                if (e1 < m) v1 = x4[(size_t)s1 * 8 + li];
                if (e2 < m) v2 = x4[(size_t)s2 * 8 + li];
                if (e3 < m) v3 = x4[(size_t)s3 * 8 + li];
                if (e4 < m) v4 = x4[(size_t)s4 * 8 + li];
                a0 += bflo(v1.x); a1 += bfhi(v1.x);
                a2 += bflo(v1.y); a3 += bfhi(v1.y);
                a4 += bflo(v1.z); a5 += bfhi(v1.z);
                a6 += bflo(v1.w); a7 += bfhi(v1.w);
                a0 += bflo(v2.x); a1 += bfhi(v2.x);
                a2 += bflo(v2.y); a3 += bfhi(v2.y);
                a4 += bflo(v2.z); a5 += bfhi(v2.z);
                a6 += bflo(v2.w); a7 += bfhi(v2.w);
                a0 += bflo(v3.x); a1 += bfhi(v3.x);
                a2 += bflo(v3.y); a3 += bfhi(v3.y);
                a4 += bflo(v3.z); a5 += bfhi(v3.z);
                a6 += bflo(v3.w); a7 += bfhi(v3.w);
                a0 += bflo(v4.x); a1 += bfhi(v4.x);
                a2 += bflo(v4.y); a3 += bfhi(v4.y);
                a4 += bflo(v4.z); a5 += bfhi(v4.z);
                a6 += bflo(v4.w); a7 += bfhi(v4.w);
            }
        }
        #pragma unroll
        for (int off = 8; off <= 32; off <<= 1) {
            a0 += __shfl_xor(a0, off); a1 += __shfl_xor(a1, off);
            a2 += __shfl_xor(a2, off); a3 += __shfl_xor(a3, off);
            a4 += __shfl_xor(a4, off); a5 += __shfl_xor(a5, off);
            a6 += __shfl_xor(a6, off); a7 += __shfl_xor(a7, off);
        }
        if (sub == 0) {                       // 8 lanes store the 128B row
            uint4 o;
            o.x = packbf(a0, a1);
            o.y = packbf(a2, a3);
            o.z = packbf(a4, a5);
            o.w = packbf(a6, a7);
            ((uint4*)y)[(size_t)node * 8 + li] = o;
        }
    }
}

// --- GEMM + epilogue: Z[m] = relu(ndst[m]*(S[m]@W) + b) [* nsrc[m]] --------
// Block = 4 waves, each wave one 16-row M-tile. bf16 MFMA 16x16x32.
// A frag: lane holds A[m=lane&15][k=quad*8+j]. D: col=lane&15, row=quad*4+reg.
__global__ __launch_bounds__(256) void gemm_kernel(
    const unsigned short* __restrict__ A, const float* __restrict__ W,
    const float* __restrict__ b, const float* __restrict__ ndst,
    const float* __restrict__ nsrc, unsigned short* __restrict__ Z,
    int M, int scale_out)
{
    int t = threadIdx.x, lane = t & 63, w = t >> 6;
    int col = lane & 15, quad = lane >> 4;
    bf16x8 bfrag[4][2];
    #pragma unroll
    for (int nt = 0; nt < 4; nt++)
        #pragma unroll
        for (int ks = 0; ks < 2; ks++)
            #pragma unroll
            for (int j = 0; j < 8; j++)
                bfrag[nt][ks][j] =
                    (short)f2bf(W[(ks * 32 + quad * 8 + j) * 64 + nt * 16 + col]);
    float bias[4];
    #pragma unroll
    for (int nt = 0; nt < 4; nt++) bias[nt] = b[nt * 16 + col];

    int mbase = blockIdx.x * 64 + w * 16;
    if (mbase >= M) return;
    int row = min(mbase + col, M - 1);
    const uint4* a4 = (const uint4*)A;
    union { uint4 u; bf16x8 v; } a0, a1;
    a0.u = a4[(size_t)row * 8 + quad];
    a1.u = a4[(size_t)row * 8 + 4 + quad];

    float nd[4], ns[4];
    #pragma unroll
    for (int r = 0; r < 4; r++) {
        int m = min(mbase + quad * 4 + r, M - 1);
        nd[r] = ndst[m];
        ns[r] = scale_out ? nsrc[m] : 1.f;
    }

    #pragma unroll
    for (int nt = 0; nt < 4; nt++) {
        f32x4 acc = {0.f, 0.f, 0.f, 0.f};
        acc = __builtin_amdgcn_mfma_f32_16x16x32_bf16(a0.v, bfrag[nt][0], acc, 0, 0, 0);
        acc = __builtin_amdgcn_mfma_f32_16x16x32_bf16(a1.v, bfrag[nt][1], acc, 0, 0, 0);
        #pragma unroll
        for (int r = 0; r < 4; r++) {
            int m = mbase + quad * 4 + r;
            if (m < M)
                Z[(size_t)m * 64 + nt * 16 + col] =
                    f2bf(fmaxf(nd[r] * acc[r] + bias[nt], 0.f) * ns[r]);
        }
    }
}

// --- per-graph mean pool + 64x5 classifier (block per graph) ---------------
__global__ __launch_bounds__(256) void pool_kernel(
    const unsigned short* __restrict__ h2, const int* __restrict__ goffs,
    const float* __restrict__ Wc, const float* __restrict__ bc,
    float* __restrict__ out)
{
    int g = blockIdx.x;
    int lane = threadIdx.x & 63;
    int w = threadIdx.x >> 6;
    int s = goffs[g], e = goffs[g + 1];
    float acc = 0.f;
    for (int i = s + w; i < e; i += 4) acc += bf1(h2[i * 64 + lane]);
    __shared__ float red[4][64];
    red[w][lane] = acc;
    __syncthreads();
    if (w == 0) {
        float tot = red[0][lane] + red[1][lane] + red[2][lane] + red[3][lane];
        float mean = tot / (float)max(e - s, 1);
        float wc[5];
        #pragma unroll
        for (int c = 0; c < 5; c++) wc[c] = Wc[lane * 5 + c];
        #pragma unroll
        for (int c = 0; c < 5; c++) {
            float p = mean * wc[c];
            #pragma unroll
            for (int off = 32; off; off >>= 1) p += __shfl_down(p, off);
            if (lane == 0) out[g * 5 + c] = p + bc[c];
        }
    }
}

extern "C" void kernel_launch(void* const* d_in, const int* in_sizes, int n_in,
                              void* d_out, int out_size, void* d_ws, size_t ws_size,
                              hipStream_t stream)
{
    const float* h    = (const float*)d_in[0];
    const int*   src  = (const int*)d_in[1];
    const int*   dst  = (const int*)d_in[2];
    const int*   gids = (const int*)d_in[3];
    const float* W1   = (const float*)d_in[4];
    const float* b1   = (const float*)d_in[5];
    const float* W2   = (const float*)d_in[6];
    const float* b2   = (const float*)d_in[7];
    const float* Wc   = (const float*)d_in[8];
    const float* bc   = (const float*)d_in[9];
    float* out = (float*)d_out;

    const int N = in_sizes[0] / 64;
    const int E = in_sizes[1];
    const int G = out_size / 5;
    const int NB = (N + 511) >> 9;
    const int NBB = (N + 255) / 256;        // bounds blocks

    auto align = [](size_t x) { return (x + 255) & ~(size_t)255; };
    char* p = (char*)d_ws;
    int* histD   = (int*)p;            p += align((size_t)NBK * 256 * 4);
    int* histS   = (int*)p;            p += align((size_t)NBK * 256 * 4);
    int* btotD   = (int*)p;            p += align((size_t)NBK * 4);
    int* btotS   = (int*)p;            p += align((size_t)NBK * 4);
    int* baseD   = (int*)p;            p += align((size_t)(NBK + 1) * 4);
    int* baseS   = (int*)p;            p += align((size_t)(NBK + 1) * 4);
    int* row_offs= (int*)p;            p += align((size_t)(N + 1) * 4);
    float* nsrc  = (float*)p;          p += align((size_t)N * 4);
    float* ndst  = (float*)p;          p += align((size_t)N * 4);
    int* goffs   = (int*)p;            p += align((size_t)(G + 1) * 4);
    int* pack    = (int*)p;            p += align((size_t)E * 4);
    unsigned short* sloc = (unsigned short*)p; p += align((size_t)E * 2);
    int* col     = (int*)p;            p += align((size_t)E * 4);
    unsigned short* xs  = (unsigned short*)p; p += align((size_t)N * 64 * 2);
    unsigned short* s1  = (unsigned short*)p; p += align((size_t)N * 64 * 2);
    unsigned short* h1s = (unsigned short*)p; p += align((size_t)N * 64 * 2);
    unsigned short* s2  = s1;   // alias: s1 dead after gemm1
    unsigned short* h2  = xs;   // alias: xs dead after agg1

    p1_hist<<<HB + NBB, 256, 0, stream>>>(src, dst, histD, histS,
                                          gids, goffs, E, NB, N, G);
    p2_scanblocks<<<2 * NB, 256, 0, stream>>>(histD, histS, btotD, btotS, NB);
    p3_scanbuckets<<<1, 256, 0, stream>>>(btotD, btotS, baseD, baseS,
                                          row_offs, E, NB, N);
    p4_scatter<<<256, 256, 0, stream>>>(src, dst, histD, histS, baseD, baseS,
                                        pack, sloc, E, NB);
    p5_build<<<2 * NB, 256, 0, stream>>>(pack, sloc, baseD, baseS, col,
                                         row_offs, nsrc, ndst, h, xs, N, NB);

    agg_kernel<<<2048, 256, 0, stream>>>(xs, s1, col, row_offs, N);
    gemm_kernel<<<(N + 63) / 64, 256, 0, stream>>>(s1, W1, b1, ndst, nsrc,
                                                   h1s, N, 1);
    agg_kernel<<<2048, 256, 0, stream>>>(h1s, s2, col, row_offs, N);
    gemm_kernel<<<(N + 63) / 64, 256, 0, stream>>>(s2, W2, b2, ndst, nsrc,
                                                   h2, N, 0);

    pool_kernel<<<G, 256, 0, stream>>>(h2, goffs, Wc, bc, out);
}